// Round 1
// 730.484 us; speedup vs baseline: 1.0941x; 1.0941x over previous
//
#include <hip/hip_runtime.h>
#include <hip/hip_bf16.h>
#include <stdint.h>

// Problem constants
constexpr int Bb = 2;
constexpr int Ll = 2048;
constexpr int Dd = 1024;
constexpr int Nn = 16;
constexpr int NB = Dd * Nn;    // 16384
constexpr int SL = 64;         // scan segment length
constexpr int NCH = Bb * Dd;   // 2048 channels
constexpr int KCAT = 3 * Dd;   // 3072: [hi|lo|hi] x [Whi|Whi|Wlo]

typedef __bf16 bf16_t;
typedef __bf16 bf16x8 __attribute__((ext_vector_type(8)));
typedef __bf16 bf16x4 __attribute__((ext_vector_type(4)));
typedef float f32x4 __attribute__((ext_vector_type(4)));

// async global->LDS, 16 B per lane. LDS dest = wave-uniform base + lane*16
// (m104/m108); passing per-lane ptr base+lane*16 matches that exactly.
__device__ inline void gld_lds16(const void* g, void* l) {
    __builtin_amdgcn_global_load_lds(
        (const __attribute__((address_space(1))) unsigned int*)g,
        (__attribute__((address_space(3))) unsigned int*)l, 16, 0, 0);
}

// ---------- fp32 -> bf16 conversion (vectorized, grid-stride) ----------
__global__ __launch_bounds__(256) void cvt_bf16(const float* __restrict__ s,
                                                bf16_t* __restrict__ d, int n4) {
    int i = blockIdx.x * 256 + threadIdx.x;
    const int stride = gridDim.x * 256;
    const float4* s4 = (const float4*)s;
    bf16x4* d4 = (bf16x4*)d;
    for (; i < n4; i += stride) {
        float4 v = s4[i];
        bf16x4 o = {(bf16_t)v.x, (bf16_t)v.y, (bf16_t)v.z, (bf16_t)v.w};
        d4[i] = o;
    }
}

// u_cat row = [u_hi (1024) | u_lo (1024) | u_hi (1024)], one thread per float4
__global__ __launch_bounds__(256) void build_ucat(const float* __restrict__ u,
                                                  bf16_t* __restrict__ ucat) {
    const int i = blockIdx.x * 256 + threadIdx.x;
    const int row = i >> 8;
    const int c = (i & 255) << 2;
    float4 v = ((const float4*)u)[i];
    bf16x4 hi = {(bf16_t)v.x, (bf16_t)v.y, (bf16_t)v.z, (bf16_t)v.w};
    bf16x4 lo = {(bf16_t)(v.x - (float)hi.x), (bf16_t)(v.y - (float)hi.y),
                 (bf16_t)(v.z - (float)hi.z), (bf16_t)(v.w - (float)hi.w)};
    bf16_t* r = ucat + (size_t)row * KCAT;
    *(bf16x4*)(r + c) = hi;
    *(bf16x4*)(r + Dd + c) = lo;
    *(bf16x4*)(r + 2 * Dd + c) = hi;
}

// W_cat row = [W_hi | W_hi | W_lo]
__global__ __launch_bounds__(256) void build_wcat(const float* __restrict__ w,
                                                  bf16_t* __restrict__ wcat) {
    const int i = blockIdx.x * 256 + threadIdx.x;
    const int row = i >> 8;
    const int c = (i & 255) << 2;
    float4 v = ((const float4*)w)[i];
    bf16x4 hi = {(bf16_t)v.x, (bf16_t)v.y, (bf16_t)v.z, (bf16_t)v.w};
    bf16x4 lo = {(bf16_t)(v.x - (float)hi.x), (bf16_t)(v.y - (float)hi.y),
                 (bf16_t)(v.z - (float)hi.z), (bf16_t)(v.w - (float)hi.w)};
    bf16_t* r = wcat + (size_t)row * KCAT;
    *(bf16x4*)(r + c) = hi;
    *(bf16x4*)(r + Dd + c) = hi;
    *(bf16x4*)(r + 2 * Dd + c) = lo;
}

// ---------- legacy 128x128 MFMA GEMM (kept for dt GEMM + fallback) ----------
template <int EP, typename OutT>
__global__ __launch_bounds__(256) void gemm_mfma(
    const bf16_t* __restrict__ Abase, int CL, int l0, int K,
    const bf16_t* __restrict__ W, const float* __restrict__ b1,
    const float* __restrict__ b2, OutT* __restrict__ C, int N)
{
    __shared__ bf16_t As[128 * 32];
    __shared__ bf16_t Bs[128 * 32];

    const int tid = threadIdx.x;
    const int bn = blockIdx.x * 128;
    const int rglob = blockIdx.y * 128;
    const int batch = rglob / CL;
    const int rin = rglob % CL;
    const bf16_t* Ap = Abase + ((size_t)batch * Ll + l0 + rin) * K;
    const bf16_t* Wp = W + (size_t)bn * K;
    OutT* Cp = C + (size_t)rglob * N;

    const int sr = tid >> 2;
    const int sc = (tid & 3) << 3;
    char* ldsA = (char*)As + tid * 16;
    char* ldsB = (char*)Bs + tid * 16;

    const int lane = tid & 63;
    const int wid = tid >> 6;
    const int wm = (wid & 1) << 6;
    const int wn = (wid >> 1) << 6;
    const int lr = lane & 15;
    const int lq = lane >> 4;

    f32x4 acc[4][4] = {};

    for (int k0 = 0; k0 < K; k0 += 32) {
        __syncthreads();
        gld_lds16(Ap + (size_t)sr * K + k0 + sc, ldsA);
        gld_lds16(Ap + (size_t)(sr + 64) * K + k0 + sc, ldsA + 4096);
        gld_lds16(Wp + (size_t)sr * K + k0 + sc, ldsB);
        gld_lds16(Wp + (size_t)(sr + 64) * K + k0 + sc, ldsB + 4096);
        __syncthreads();

        bf16x8 af[4], bfr[4];
#pragma unroll
        for (int mi = 0; mi < 4; ++mi)
            af[mi] = *(const bf16x8*)&As[(wm + mi * 16 + lr) * 32 + lq * 8];
#pragma unroll
        for (int ni = 0; ni < 4; ++ni)
            bfr[ni] = *(const bf16x8*)&Bs[(wn + ni * 16 + lr) * 32 + lq * 8];
#pragma unroll
        for (int mi = 0; mi < 4; ++mi)
#pragma unroll
            for (int ni = 0; ni < 4; ++ni)
                acc[mi][ni] = __builtin_amdgcn_mfma_f32_16x16x32_bf16(
                    af[mi], bfr[ni], acc[mi][ni], 0, 0, 0);
    }

#pragma unroll
    for (int ni = 0; ni < 4; ++ni) {
        const int col = bn + wn + ni * 16 + lr;
        const float bc = b1[col] + (EP == 1 ? b2[col] : 0.f);
#pragma unroll
        for (int mi = 0; mi < 4; ++mi)
#pragma unroll
            for (int i = 0; i < 4; ++i) {
                float v = acc[mi][ni][i] + bc;
                if (EP == 1) v = (v > 20.f) ? v : log1pf(__expf(v));
                Cp[(size_t)(wm + mi * 16 + lq * 4 + i) * N + col] = (OutT)v;
            }
    }
}

// ---------- 256x256 8-phase MFMA GEMM (T2+T3+T4+T5; m201-style template) ----
// 512 threads = 8 waves (2M x 4N); per-wave 128x64 output = 8x4 16x16 frags.
// BK=64 -> 4 phases per K-tile, 16 MFMA/phase. LDS: 2 buffers x (A 32K + B 32K)
// = 128 KiB dynamic. Staging is global_load_lds (linear dest); the st-swizzle
// (byte ^= (row&7)<<4) is applied by inverse-swizzling the GLOBAL source and
// XOR-ing the ds_read address (rule 21: both-sides-or-neither).
// Schedule per iteration t (compute K-tile t from buf[t&1]):
//   p0: stage A0(t+1)->buf^1 ; ds_read all 8 B-frags + A mi{0,1}; bar; 16 MFMA; bar
//   p1: stage A1(t+1)->buf^1 ; ds_read A mi{2,3};               bar; 16 MFMA; bar
//   p2: stage B0(t+2)->buf   ; ds_read A mi{4,5};               bar; 16 MFMA; bar
//        (B region of buf is read-free after p0's end barrier)
//   p3: stage B1(t+2)->buf   ; ds_read A mi{6,7};               bar; 16 MFMA;
//        s_waitcnt vmcnt(4)  (oldest 8 = all halves of t+1 landed; B(t+2) stays
//        in flight across the barrier -> counted-vmcnt pipeline, never 0); bar
__global__ __launch_bounds__(512, 2) void gemm256(
    const bf16_t* __restrict__ Abase, int CL, int l0, int K,
    const bf16_t* __restrict__ W, const float* __restrict__ b1,
    bf16_t* __restrict__ C, int N)
{
    extern __shared__ char smem[];
    const int tid = threadIdx.x;
    const int bn = blockIdx.x * 256;
    const int rglob = blockIdx.y * 256;
    const int batch = rglob / CL;
    const int rin = rglob % CL;
    const bf16_t* Ap = Abase + ((size_t)batch * Ll + l0 + rin) * K;
    const bf16_t* Wp = W + (size_t)bn * K;
    bf16_t* Cp = C + (size_t)rglob * N;

    const int lane = tid & 63;
    const int wid = tid >> 6;
    const int wr = wid >> 2;       // 0..1  (M half)
    const int wc = wid & 3;        // 0..3  (N quarter)
    const int lr = lane & 15;
    const int lq = lane >> 4;
    const int NT = K >> 6;         // K-tiles of 64

    // staging constants: 2 chunks of 16B per thread per half-tile (128 rows x 64k)
    const int c0 = tid, c1 = tid + 512;
    const int r0 = c0 >> 3, r1 = c1 >> 3;                 // row within half
    const int kb0 = ((c0 & 7) << 3) ^ ((r0 & 7) << 3);    // inverse-swizzled k elems
    const int kb1 = ((c1 & 7) << 3) ^ ((r1 & 7) << 3);

    auto stage = [&](const bf16_t* src, char* dst, int tt, int h) {
        gld_lds16(src + (size_t)(h * 128 + r0) * K + tt * 64 + kb0,
                  dst + h * 16384 + c0 * 16);
        gld_lds16(src + (size_t)(h * 128 + r1) * K + tt * 64 + kb1,
                  dst + h * 16384 + c1 * 16);
    };

    // prologue: K-tile 0 (A+B) -> buf0 ; B halves of K-tile 1 -> buf1
    stage(Ap, smem, 0, 0);
    stage(Ap, smem, 0, 1);
    stage(Wp, smem + 32768, 0, 0);
    stage(Wp, smem + 32768, 0, 1);
    if (NT > 1) {
        stage(Wp, smem + 65536 + 32768, 1, 0);
        stage(Wp, smem + 65536 + 32768, 1, 1);
        asm volatile("s_waitcnt vmcnt(4)" ::: "memory");   // K-tile0's 8 loads done
    } else {
        asm volatile("s_waitcnt vmcnt(0)" ::: "memory");
    }
    __builtin_amdgcn_s_barrier();

    f32x4 acc[8][4] = {};
    const int xsw = (lr & 7) << 4;     // read-side XOR swizzle (bytes)

    for (int t = 0; t < NT; ++t) {
        char* Ard = smem + ((t & 1) ? 65536 : 0);
        char* Brd = Ard + 32768;
        char* Awr = smem + ((t & 1) ? 0 : 65536);   // A(t+1) -> other buffer
        char* Bwr = Brd;                            // B(t+2) -> this buffer

        bf16x8 bfr[2][4];
#pragma unroll
        for (int p = 0; p < 4; ++p) {
            // --- stage one half-tile (issue early; lands under MFMA) ---
            if (p == 0) { if (t + 1 < NT) stage(Ap, Awr, t + 1, 0); }
            if (p == 1) { if (t + 1 < NT) stage(Ap, Awr, t + 1, 1); }
            if (p == 2) { if (t + 2 < NT) stage(Wp, Bwr, t + 2, 0); }
            if (p == 3) { if (t + 2 < NT) stage(Wp, Bwr, t + 2, 1); }

            // --- ds_reads (swizzle-free throughput: 64 lanes hit 64 distinct
            //     16B cells, 8 accesses/bank) ---
            if (p == 0) {
#pragma unroll
                for (int ks = 0; ks < 2; ++ks)
#pragma unroll
                    for (int ni = 0; ni < 4; ++ni)
                        bfr[ks][ni] = *(const bf16x8*)(Brd +
                            (wc * 64 + ni * 16 + lr) * 128 +
                            ((ks * 64 + lq * 16) ^ xsw));
            }
            bf16x8 a0k0 = *(const bf16x8*)(Ard +
                (wr * 128 + (2 * p) * 16 + lr) * 128 + ((lq * 16) ^ xsw));
            bf16x8 a0k1 = *(const bf16x8*)(Ard +
                (wr * 128 + (2 * p) * 16 + lr) * 128 + ((64 + lq * 16) ^ xsw));
            bf16x8 a1k0 = *(const bf16x8*)(Ard +
                (wr * 128 + (2 * p + 1) * 16 + lr) * 128 + ((lq * 16) ^ xsw));
            bf16x8 a1k1 = *(const bf16x8*)(Ard +
                (wr * 128 + (2 * p + 1) * 16 + lr) * 128 + ((64 + lq * 16) ^ xsw));

            __builtin_amdgcn_s_barrier();
            __builtin_amdgcn_s_setprio(1);
#pragma unroll
            for (int ni = 0; ni < 4; ++ni) {
                acc[2 * p][ni] = __builtin_amdgcn_mfma_f32_16x16x32_bf16(
                    a0k0, bfr[0][ni], acc[2 * p][ni], 0, 0, 0);
                acc[2 * p][ni] = __builtin_amdgcn_mfma_f32_16x16x32_bf16(
                    a0k1, bfr[1][ni], acc[2 * p][ni], 0, 0, 0);
                acc[2 * p + 1][ni] = __builtin_amdgcn_mfma_f32_16x16x32_bf16(
                    a1k0, bfr[0][ni], acc[2 * p + 1][ni], 0, 0, 0);
                acc[2 * p + 1][ni] = __builtin_amdgcn_mfma_f32_16x16x32_bf16(
                    a1k1, bfr[1][ni], acc[2 * p + 1][ni], 0, 0, 0);
            }
            __builtin_amdgcn_s_setprio(0);
            if (p == 3) {
                if (t + 2 < NT)
                    asm volatile("s_waitcnt vmcnt(4)" ::: "memory");
                else if (t + 1 < NT)
                    asm volatile("s_waitcnt vmcnt(0)" ::: "memory");   // tail only
            }
            __builtin_amdgcn_s_barrier();
        }
    }

    // epilogue: C/D layout col = lane&15, row = (lane>>4)*4 + i (m89/m91)
#pragma unroll
    for (int ni = 0; ni < 4; ++ni) {
        const int col = bn + wc * 64 + ni * 16 + lr;
        const float bc = b1[col];
#pragma unroll
        for (int mi = 0; mi < 8; ++mi)
#pragma unroll
            for (int i = 0; i < 4; ++i)
                Cp[(size_t)(wr * 128 + mi * 16 + lq * 4 + i) * N + col] =
                    (bf16_t)(acc[mi][ni][i] + bc);
    }
}

// ---------- scan pass A: per-segment local scan (h0 = 0) ----------
__global__ __launch_bounds__(256) void scan_seg_local(
    const float* __restrict__ u, const float* __restrict__ dt,
    const bf16_t* __restrict__ Bt_c, const float* __restrict__ log_A,
    float* __restrict__ pseg, float* __restrict__ hseg, int CL, int l0)
{
    const int tid = threadIdx.x;
    const int g = tid >> 4, n = tid & 15;
    const int gid = blockIdx.x * 16 + g;
    const int ch = gid & (NCH - 1);
    const int s = gid >> 11;
    const int b = ch >> 10, d = ch & (Dd - 1);

    const float A = -__expf(log_A[d * Nn + n]);
    const float rA = 1.f / A;

    size_t idx_bn = (size_t)(b * CL + s * SL) * NB + d * Nn + n;
    size_t idx_u = ((size_t)b * Ll + l0 + s * SL) * Dd + d;

    float p = 1.f, h = 0.f;
    for (int l = 0; l < SL; ++l) {
        const float dtv = dt[idx_u];
        const float uv = u[idx_u];
        const float bv = (float)Bt_c[idx_bn];
        const float a = __expf(dtv * A);
        p *= a;
        h = a * h + (a - 1.f) * rA * bv * uv;
        idx_bn += NB; idx_u += Dd;
    }
    const size_t o = ((size_t)s * NCH + ch) * Nn + n;
    pseg[o] = p;
    hseg[o] = h;
}

// ---------- scan pass B: sequential combine across segments ----------
__global__ __launch_bounds__(256) void scan_combine(
    const float* __restrict__ pseg, const float* __restrict__ hseg,
    float* __restrict__ hin_arr, float* __restrict__ h_state,
    int NSEG, int l0)
{
    const int t = blockIdx.x * 256 + threadIdx.x;
    float hin = (l0 == 0) ? 0.f : h_state[t];
    for (int s = 0; s < NSEG; ++s) {
        const size_t o = (size_t)s * (NCH * Nn) + t;
        hin_arr[o] = hin;
        hin = pseg[o] * hin + hseg[o];
    }
    h_state[t] = hin;
}

// ---------- scan pass C: re-run segment from correct h_in, emit y ----------
__global__ __launch_bounds__(256) void scan_seg_final(
    const float* __restrict__ u, const float* __restrict__ dt,
    const bf16_t* __restrict__ Bt_c, const bf16_t* __restrict__ Ct_c,
    const float* __restrict__ log_A, const float* __restrict__ D_skip,
    const float* __restrict__ hin_arr, float* __restrict__ y, int CL, int l0)
{
    const int tid = threadIdx.x;
    const int g = tid >> 4, n = tid & 15;
    const int gid = blockIdx.x * 16 + g;
    const int ch = gid & (NCH - 1);
    const int s = gid >> 11;
    const int b = ch >> 10, d = ch & (Dd - 1);

    const float A = -__expf(log_A[d * Nn + n]);
    const float rA = 1.f / A;
    const float Dsk = D_skip[d];

    size_t idx_bn = (size_t)(b * CL + s * SL) * NB + d * Nn + n;
    size_t idx_u = ((size_t)b * Ll + l0 + s * SL) * Dd + d;

    float h = hin_arr[((size_t)s * NCH + ch) * Nn + n];
    for (int l = 0; l < SL; ++l) {
        const float dtv = dt[idx_u];
        const float uv = u[idx_u];
        const float bv = (float)Bt_c[idx_bn];
        const float cv = (float)Ct_c[idx_bn];
        const float a = __expf(dtv * A);
        h = a * h + (a - 1.f) * rA * bv * uv;
        float p = cv * h;
        p += __shfl_xor(p, 1);
        p += __shfl_xor(p, 2);
        p += __shfl_xor(p, 4);
        p += __shfl_xor(p, 8);
        if (n == 0) y[idx_u] = p + Dsk * uv;
        idx_bn += NB; idx_u += Dd;
    }
}

// ---------- host ----------
static inline size_t al256(size_t x) { return (x + 255) & ~(size_t)255; }

extern "C" void kernel_launch(void* const* d_in, const int* in_sizes, int n_in,
                              void* d_out, int out_size, void* d_ws, size_t ws_size,
                              hipStream_t stream) {
    const float* u       = (const float*)d_in[0];
    const float* log_A   = (const float*)d_in[1];
    const float* D_skip  = (const float*)d_in[2];
    const float* dt_bias = (const float*)d_in[3];
    const float* W_dt    = (const float*)d_in[4];
    const float* b_dt    = (const float*)d_in[5];
    const float* W_B     = (const float*)d_in[6];
    const float* b_B     = (const float*)d_in[7];
    const float* W_C     = (const float*)d_in[8];
    const float* b_C     = (const float*)d_in[9];
    float* y = (float*)d_out;

    // allow 128 KiB dynamic LDS for gemm256 (capture-safe host call)
    hipFuncSetAttribute(reinterpret_cast<const void*>(gemm256),
                        hipFuncAttributeMaxDynamicSharedMemorySize, 131072);

    const size_t sz_ubf  = al256((size_t)Bb * Ll * Dd * 2);
    const size_t sz_w    = al256((size_t)NB * Dd * 2);
    const size_t sz_h    = al256((size_t)NCH * Nn * 4);
    const size_t sz_dtf  = al256((size_t)Bb * Ll * Dd * 4);
    const size_t sz_ucat = al256((size_t)Bb * Ll * KCAT * 2);
    const size_t sz_wcat = al256((size_t)Dd * KCAT * 2);

    int CL = 128;
    const int cands[5] = {2048, 1024, 512, 256, 128};
    for (int i = 0; i < 5; ++i) {
        const int c = cands[i];
        const int nseg = c / SL;
        const size_t seg = 3 * al256((size_t)nseg * NCH * Nn * 4);
        const size_t chunk = 2 * al256((size_t)2 * c * NB * 2);
        const size_t ovl = sz_ucat + sz_wcat;
        const size_t need = sz_ubf + 2 * sz_w + sz_h + sz_dtf + seg +
                            (chunk > ovl ? chunk : ovl);
        if (need <= ws_size) { CL = c; break; }
    }
    const int NSEG = CL / SL;

    char* p = (char*)d_ws;
    bf16_t* u_bf   = (bf16_t*)p; p += sz_ubf;
    bf16_t* wB_bf  = (bf16_t*)p; p += sz_w;
    bf16_t* wC_bf  = (bf16_t*)p; p += sz_w;
    float* h_state = (float*)p; p += sz_h;
    float* dt_full = (float*)p; p += sz_dtf;
    const size_t sz_seg1 = al256((size_t)NSEG * NCH * Nn * 4);
    float* pseg    = (float*)p; p += sz_seg1;
    float* hseg    = (float*)p; p += sz_seg1;
    float* hin_arr = (float*)p; p += sz_seg1;
    char* chunk0 = p;
    bf16_t* Bt_c = (bf16_t*)chunk0;
    bf16_t* Ct_c = (bf16_t*)(chunk0 + al256((size_t)2 * CL * NB * 2));
    bf16_t* u_cat = (bf16_t*)chunk0;
    bf16_t* w_cat = (bf16_t*)(chunk0 + sz_ucat);

    cvt_bf16<<<2048, 256, 0, stream>>>(u, u_bf, Bb * Ll * Dd / 4);
    cvt_bf16<<<2048, 256, 0, stream>>>(W_B, wB_bf, NB * Dd / 4);
    cvt_bf16<<<2048, 256, 0, stream>>>(W_C, wC_bf, NB * Dd / 4);
    build_ucat<<<Bb * Ll * Dd / 4 / 256, 256, 0, stream>>>(u, u_cat);
    build_wcat<<<Dd * Dd / 4 / 256, 256, 0, stream>>>(W_dt, w_cat);

    // dt GEMM stays on the 128^2 kernel (256-block grid saturates; 256^2 would
    // leave 3/4 of the CUs idle at N=1024)
    gemm_mfma<1, float><<<dim3(Dd / 128, Bb * Ll / 128), 256, 0, stream>>>(
        u_cat, Ll, 0, KCAT, w_cat, b_dt, dt_bias, dt_full, Dd);

    const bool use256 = (CL % 256 == 0);
    for (int l0 = 0; l0 < Ll; l0 += CL) {
        if (use256) {
            gemm256<<<dim3(NB / 256, 2 * CL / 256), 512, 131072, stream>>>(
                u_bf, CL, l0, Dd, wB_bf, b_B, Bt_c, NB);
            gemm256<<<dim3(NB / 256, 2 * CL / 256), 512, 131072, stream>>>(
                u_bf, CL, l0, Dd, wC_bf, b_C, Ct_c, NB);
        } else {
            gemm_mfma<0, bf16_t><<<dim3(NB / 128, 2 * CL / 128), 256, 0, stream>>>(
                u_bf, CL, l0, Dd, wB_bf, b_B, nullptr, Bt_c, NB);
            gemm_mfma<0, bf16_t><<<dim3(NB / 128, 2 * CL / 128), 256, 0, stream>>>(
                u_bf, CL, l0, Dd, wC_bf, b_C, nullptr, Ct_c, NB);
        }
        scan_seg_local<<<dim3(128 * NSEG), 256, 0, stream>>>(
            u, dt_full, Bt_c, log_A, pseg, hseg, CL, l0);
        scan_combine<<<dim3(128), 256, 0, stream>>>(
            pseg, hseg, hin_arr, h_state, NSEG, l0);
        scan_seg_final<<<dim3(128 * NSEG), 256, 0, stream>>>(
            u, dt_full, Bt_c, Ct_c, log_A, D_skip, hin_arr, y, CL, l0);
    }
}

// Round 3
// 689.056 us; speedup vs baseline: 1.1599x; 1.0601x over previous
//
#include <hip/hip_runtime.h>
#include <hip/hip_bf16.h>
#include <stdint.h>

// Problem constants
constexpr int Bb = 2;
constexpr int Ll = 2048;
constexpr int Dd = 1024;
constexpr int Nn = 16;
constexpr int NB = Dd * Nn;    // 16384
constexpr int SL = 64;         // scan segment length
constexpr int NCH = Bb * Dd;   // 2048 channels
constexpr int KCAT = 3 * Dd;   // 3072: [hi|lo|hi] x [Whi|Whi|Wlo]

typedef __bf16 bf16_t;
typedef __bf16 bf16x8 __attribute__((ext_vector_type(8)));
typedef __bf16 bf16x4 __attribute__((ext_vector_type(4)));
typedef float f32x4 __attribute__((ext_vector_type(4)));

// async global->LDS, 16 B per lane. LDS dest = wave-uniform base + lane*16
// (m104/m108); passing per-lane ptr base+lane*16 matches that exactly.
__device__ inline void gld_lds16(const void* g, void* l) {
    __builtin_amdgcn_global_load_lds(
        (const __attribute__((address_space(1))) unsigned int*)g,
        (__attribute__((address_space(3))) unsigned int*)l, 16, 0, 0);
}

// ---------- fp32 -> bf16 conversion (vectorized, grid-stride) ----------
__global__ __launch_bounds__(256) void cvt_bf16(const float* __restrict__ s,
                                                bf16_t* __restrict__ d, int n4) {
    int i = blockIdx.x * 256 + threadIdx.x;
    const int stride = gridDim.x * 256;
    const float4* s4 = (const float4*)s;
    bf16x4* d4 = (bf16x4*)d;
    for (; i < n4; i += stride) {
        float4 v = s4[i];
        bf16x4 o = {(bf16_t)v.x, (bf16_t)v.y, (bf16_t)v.z, (bf16_t)v.w};
        d4[i] = o;
    }
}

// u_cat row = [u_hi (1024) | u_lo (1024) | u_hi (1024)], one thread per float4
__global__ __launch_bounds__(256) void build_ucat(const float* __restrict__ u,
                                                  bf16_t* __restrict__ ucat) {
    const int i = blockIdx.x * 256 + threadIdx.x;
    const int row = i >> 8;
    const int c = (i & 255) << 2;
    float4 v = ((const float4*)u)[i];
    bf16x4 hi = {(bf16_t)v.x, (bf16_t)v.y, (bf16_t)v.z, (bf16_t)v.w};
    bf16x4 lo = {(bf16_t)(v.x - (float)hi.x), (bf16_t)(v.y - (float)hi.y),
                 (bf16_t)(v.z - (float)hi.z), (bf16_t)(v.w - (float)hi.w)};
    bf16_t* r = ucat + (size_t)row * KCAT;
    *(bf16x4*)(r + c) = hi;
    *(bf16x4*)(r + Dd + c) = lo;
    *(bf16x4*)(r + 2 * Dd + c) = hi;
}

// W_cat row = [W_hi | W_hi | W_lo]
__global__ __launch_bounds__(256) void build_wcat(const float* __restrict__ w,
                                                  bf16_t* __restrict__ wcat) {
    const int i = blockIdx.x * 256 + threadIdx.x;
    const int row = i >> 8;
    const int c = (i & 255) << 2;
    float4 v = ((const float4*)w)[i];
    bf16x4 hi = {(bf16_t)v.x, (bf16_t)v.y, (bf16_t)v.z, (bf16_t)v.w};
    bf16x4 lo = {(bf16_t)(v.x - (float)hi.x), (bf16_t)(v.y - (float)hi.y),
                 (bf16_t)(v.z - (float)hi.z), (bf16_t)(v.w - (float)hi.w)};
    bf16_t* r = wcat + (size_t)row * KCAT;
    *(bf16x4*)(r + c) = hi;
    *(bf16x4*)(r + Dd + c) = hi;
    *(bf16x4*)(r + 2 * Dd + c) = lo;
}

// ---------- legacy 128x128 MFMA GEMM (fallback only, CL%256 != 0) ----------
template <int EP, typename OutT>
__global__ __launch_bounds__(256) void gemm_mfma(
    const bf16_t* __restrict__ Abase, int CL, int l0, int K,
    const bf16_t* __restrict__ W, const float* __restrict__ b1,
    const float* __restrict__ b2, OutT* __restrict__ C, int N)
{
    __shared__ bf16_t As[128 * 32];
    __shared__ bf16_t Bs[128 * 32];

    const int tid = threadIdx.x;
    const int bn = blockIdx.x * 128;
    const int rglob = blockIdx.y * 128;
    const int batch = rglob / CL;
    const int rin = rglob % CL;
    const bf16_t* Ap = Abase + ((size_t)batch * Ll + l0 + rin) * K;
    const bf16_t* Wp = W + (size_t)bn * K;
    OutT* Cp = C + (size_t)rglob * N;

    const int sr = tid >> 2;
    const int sc = (tid & 3) << 3;
    char* ldsA = (char*)As + tid * 16;
    char* ldsB = (char*)Bs + tid * 16;

    const int lane = tid & 63;
    const int wid = tid >> 6;
    const int wm = (wid & 1) << 6;
    const int wn = (wid >> 1) << 6;
    const int lr = lane & 15;
    const int lq = lane >> 4;

    f32x4 acc[4][4] = {};

    for (int k0 = 0; k0 < K; k0 += 32) {
        __syncthreads();
        gld_lds16(Ap + (size_t)sr * K + k0 + sc, ldsA);
        gld_lds16(Ap + (size_t)(sr + 64) * K + k0 + sc, ldsA + 4096);
        gld_lds16(Wp + (size_t)sr * K + k0 + sc, ldsB);
        gld_lds16(Wp + (size_t)(sr + 64) * K + k0 + sc, ldsB + 4096);
        __syncthreads();

        bf16x8 af[4], bfr[4];
#pragma unroll
        for (int mi = 0; mi < 4; ++mi)
            af[mi] = *(const bf16x8*)&As[(wm + mi * 16 + lr) * 32 + lq * 8];
#pragma unroll
        for (int ni = 0; ni < 4; ++ni)
            bfr[ni] = *(const bf16x8*)&Bs[(wn + ni * 16 + lr) * 32 + lq * 8];
#pragma unroll
        for (int mi = 0; mi < 4; ++mi)
#pragma unroll
            for (int ni = 0; ni < 4; ++ni)
                acc[mi][ni] = __builtin_amdgcn_mfma_f32_16x16x32_bf16(
                    af[mi], bfr[ni], acc[mi][ni], 0, 0, 0);
    }

#pragma unroll
    for (int ni = 0; ni < 4; ++ni) {
        const int col = bn + wn + ni * 16 + lr;
        const float bc = b1[col] + (EP == 1 ? b2[col] : 0.f);
#pragma unroll
        for (int mi = 0; mi < 4; ++mi)
#pragma unroll
            for (int i = 0; i < 4; ++i) {
                float v = acc[mi][ni][i] + bc;
                if (EP == 1) v = (v > 20.f) ? v : log1pf(__expf(v));
                Cp[(size_t)(wm + mi * 16 + lq * 4 + i) * N + col] = (OutT)v;
            }
    }
}

// ---------- dt GEMM: 128x64 tile, operand-swapped epilogue ----------
// M=4096 (all L upfront), N=1024, K=3072. Grid (16,32) = 512 blocks = 2/CU
// (the old 128^2 grid was 256 blocks = 1 wave/SIMD -> latency-bound at 10%
// MfmaUtil). 4 waves, each 64x32 = 4x2 frags. Operand-swapped MFMA
// (mfma(Wfrag, ufrag)) makes D-row index the W-frag: lane holds 4 CONSECUTIVE
// output cols of one row -> f32x4 16B stores (8/thread vs 64 scalar).
__global__ __launch_bounds__(256) void gemm_dt(
    const bf16_t* __restrict__ A, int K, const bf16_t* __restrict__ W,
    const float* __restrict__ b1, const float* __restrict__ b2,
    float* __restrict__ C)
{
    __shared__ bf16_t As[128 * 32];
    __shared__ bf16_t Bs[64 * 32];

    const int tid = threadIdx.x;
    const int bn = blockIdx.x * 64;
    const int row0 = blockIdx.y * 128;
    const bf16_t* Ap = A + (size_t)row0 * K;
    const bf16_t* Wp = W + (size_t)bn * K;
    float* Cp = C + (size_t)row0 * Dd;

    const int sr = tid >> 2;
    const int sc = (tid & 3) << 3;
    char* ldsA = (char*)As + tid * 16;
    char* ldsB = (char*)Bs + tid * 16;

    const int lane = tid & 63;
    const int wid = tid >> 6;
    const int wm = (wid & 1) << 6;     // 0/64 (rows)
    const int wn = (wid >> 1) << 5;    // 0/32 (cols)
    const int lr = lane & 15;
    const int lq = lane >> 4;

    f32x4 acc[4][2] = {};

    for (int k0 = 0; k0 < K; k0 += 32) {
        __syncthreads();
        gld_lds16(Ap + (size_t)sr * K + k0 + sc, ldsA);
        gld_lds16(Ap + (size_t)(sr + 64) * K + k0 + sc, ldsA + 4096);
        gld_lds16(Wp + (size_t)sr * K + k0 + sc, ldsB);   // 64x32 = 4 KB exactly
        __syncthreads();

        bf16x8 af[4], bfr[2];
#pragma unroll
        for (int mi = 0; mi < 4; ++mi)
            af[mi] = *(const bf16x8*)&As[(wm + mi * 16 + lr) * 32 + lq * 8];
#pragma unroll
        for (int ni = 0; ni < 2; ++ni)
            bfr[ni] = *(const bf16x8*)&Bs[(wn + ni * 16 + lr) * 32 + lq * 8];
#pragma unroll
        for (int mi = 0; mi < 4; ++mi)
#pragma unroll
            for (int ni = 0; ni < 2; ++ni)
                acc[mi][ni] = __builtin_amdgcn_mfma_f32_16x16x32_bf16(
                    bfr[ni], af[mi], acc[mi][ni], 0, 0, 0);   // SWAPPED
    }

    // swapped D layout: row = row0+wm+mi*16+lr, cols = bn+wn+ni*16+lq*4 .. +3
#pragma unroll
    for (int ni = 0; ni < 2; ++ni) {
        const int col = bn + wn + ni * 16 + lq * 4;
        const float4 ba = *(const float4*)&b1[col];
        const float4 bb = *(const float4*)&b2[col];
        const float bc[4] = {ba.x + bb.x, ba.y + bb.y, ba.z + bb.z, ba.w + bb.w};
#pragma unroll
        for (int mi = 0; mi < 4; ++mi) {
            const int row = wm + mi * 16 + lr;
            f32x4 v;
#pragma unroll
            for (int i = 0; i < 4; ++i) {
                float t = acc[mi][ni][i] + bc[i];
                v[i] = (t > 20.f) ? t : log1pf(__expf(t));
            }
            *(f32x4*)(Cp + (size_t)row * Dd + col) = v;
        }
    }
}

// ---------- fused B+C 256x256 8-phase MFMA GEMM (T1+T2+T3+T4+T5) ----------
// Stacked N = 2*NB = 32768 (x-panels 0..63 -> Bt/W_B, 64..127 -> Ct/W_C).
// 1D grid 128*NY blocks (NY = 2*CL/256). XCD swizzle: HW assigns XCD = id%8;
// decode so each XCD slot gets 8(NY)-block groups sharing one W-panel ->
// W hits L2 on 7/8 reads. Schedule identical to round-1 gemm256 (verified):
// counted vmcnt(4), never 0 in steady state. MFMA operand-swapped so the
// epilogue packs 4 consecutive cols -> 8B stores (32/thread vs 128 scalar).
__global__ __launch_bounds__(512, 2) void gemm256_bc(
    const bf16_t* __restrict__ Abase, int CL, int l0, int K,
    const bf16_t* __restrict__ WB, const bf16_t* __restrict__ WC,
    const float* __restrict__ bB, const float* __restrict__ bC,
    bf16_t* __restrict__ OB, bf16_t* __restrict__ OC)
{
    extern __shared__ char smem[];
    const int tid = threadIdx.x;

    // block decode with XCD swizzle (bijective: 128*NY blocks, NY*16 per XCD)
    const int NY = (2 * CL) >> 8;
    const int id = blockIdx.x;
    const int cx = id & 7;
    const int jj = id >> 3;
    const int x = cx * 16 + jj / NY;    // col-panel 0..127
    const int yb = jj % NY;             // row-panel

    const int rglob = yb * 256;
    const int batch = rglob / CL;
    const int rin = rglob % CL;
    const bf16_t* Ap = Abase + ((size_t)batch * Ll + l0 + rin) * K;

    const bf16_t* Wp; const float* bias; bf16_t* Co; int bn;
    if (x < 64) { Wp = WB; bias = bB; Co = OB; bn = x * 256; }
    else        { Wp = WC; bias = bC; Co = OC; bn = (x - 64) * 256; }
    Wp += (size_t)bn * K;
    bf16_t* Cp = Co + (size_t)rglob * NB;

    const int lane = tid & 63;
    const int wid = tid >> 6;
    const int wr = wid >> 2;       // 0..1  (M half)
    const int wc = wid & 3;        // 0..3  (N quarter)
    const int lr = lane & 15;
    const int lq = lane >> 4;
    const int NT = K >> 6;         // K-tiles of 64

    // staging: 2 chunks of 16B per thread per half-tile (128 rows x 64 k)
    const int c0 = tid, c1 = tid + 512;
    const int r0 = c0 >> 3, r1 = c1 >> 3;
    const int kb0 = ((c0 & 7) << 3) ^ ((r0 & 7) << 3);   // inverse-swizzled src
    const int kb1 = ((c1 & 7) << 3) ^ ((r1 & 7) << 3);

    auto stage = [&](const bf16_t* src, char* dst, int tt, int h) {
        gld_lds16(src + (size_t)(h * 128 + r0) * K + tt * 64 + kb0,
                  dst + h * 16384 + c0 * 16);
        gld_lds16(src + (size_t)(h * 128 + r1) * K + tt * 64 + kb1,
                  dst + h * 16384 + c1 * 16);
    };

    // prologue: K-tile 0 (A+B) -> buf0 ; B halves of K-tile 1 -> buf1
    stage(Ap, smem, 0, 0);
    stage(Ap, smem, 0, 1);
    stage(Wp, smem + 32768, 0, 0);
    stage(Wp, smem + 32768, 0, 1);
    if (NT > 1) {
        stage(Wp, smem + 65536 + 32768, 1, 0);
        stage(Wp, smem + 65536 + 32768, 1, 1);
        asm volatile("s_waitcnt vmcnt(4)" ::: "memory");
    } else {
        asm volatile("s_waitcnt vmcnt(0)" ::: "memory");
    }
    __builtin_amdgcn_s_barrier();

    f32x4 acc[8][4] = {};
    const int xsw = (lr & 7) << 4;     // read-side XOR swizzle (bytes)

    for (int t = 0; t < NT; ++t) {
        char* Ard = smem + ((t & 1) ? 65536 : 0);
        char* Brd = Ard + 32768;
        char* Awr = smem + ((t & 1) ? 0 : 65536);   // A(t+1) -> other buffer
        char* Bwr = Brd;                            // B(t+2) -> this buffer

        bf16x8 bfr[2][4];
#pragma unroll
        for (int p = 0; p < 4; ++p) {
            if (p == 0) { if (t + 1 < NT) stage(Ap, Awr, t + 1, 0); }
            if (p == 1) { if (t + 1 < NT) stage(Ap, Awr, t + 1, 1); }
            if (p == 2) { if (t + 2 < NT) stage(Wp, Bwr, t + 2, 0); }
            if (p == 3) { if (t + 2 < NT) stage(Wp, Bwr, t + 2, 1); }

            if (p == 0) {
#pragma unroll
                for (int ks = 0; ks < 2; ++ks)
#pragma unroll
                    for (int ni = 0; ni < 4; ++ni)
                        bfr[ks][ni] = *(const bf16x8*)(Brd +
                            (wc * 64 + ni * 16 + lr) * 128 +
                            ((ks * 64 + lq * 16) ^ xsw));
            }
            bf16x8 a0k0 = *(const bf16x8*)(Ard +
                (wr * 128 + (2 * p) * 16 + lr) * 128 + ((lq * 16) ^ xsw));
            bf16x8 a0k1 = *(const bf16x8*)(Ard +
                (wr * 128 + (2 * p) * 16 + lr) * 128 + ((64 + lq * 16) ^ xsw));
            bf16x8 a1k0 = *(const bf16x8*)(Ard +
                (wr * 128 + (2 * p + 1) * 16 + lr) * 128 + ((lq * 16) ^ xsw));
            bf16x8 a1k1 = *(const bf16x8*)(Ard +
                (wr * 128 + (2 * p + 1) * 16 + lr) * 128 + ((64 + lq * 16) ^ xsw));

            __builtin_amdgcn_s_barrier();
            __builtin_amdgcn_s_setprio(1);
#pragma unroll
            for (int ni = 0; ni < 4; ++ni) {   // SWAPPED operands
                acc[2 * p][ni] = __builtin_amdgcn_mfma_f32_16x16x32_bf16(
                    bfr[0][ni], a0k0, acc[2 * p][ni], 0, 0, 0);
                acc[2 * p][ni] = __builtin_amdgcn_mfma_f32_16x16x32_bf16(
                    bfr[1][ni], a0k1, acc[2 * p][ni], 0, 0, 0);
                acc[2 * p + 1][ni] = __builtin_amdgcn_mfma_f32_16x16x32_bf16(
                    bfr[0][ni], a1k0, acc[2 * p + 1][ni], 0, 0, 0);
                acc[2 * p + 1][ni] = __builtin_amdgcn_mfma_f32_16x16x32_bf16(
                    bfr[1][ni], a1k1, acc[2 * p + 1][ni], 0, 0, 0);
            }
            __builtin_amdgcn_s_setprio(0);
            if (p == 3) {
                if (t + 2 < NT)
                    asm volatile("s_waitcnt vmcnt(4)" ::: "memory");
                else if (t + 1 < NT)
                    asm volatile("s_waitcnt vmcnt(0)" ::: "memory");
            }
            __builtin_amdgcn_s_barrier();
        }
    }

    // swapped D layout: row = wr*128+mi*16+lr, cols = wc*64+ni*16+lq*4 .. +3
    float4 bv[4];
#pragma unroll
    for (int ni = 0; ni < 4; ++ni)
        bv[ni] = *(const float4*)&bias[bn + wc * 64 + ni * 16 + lq * 4];
#pragma unroll
    for (int mi = 0; mi < 8; ++mi) {
        const size_t rowoff = (size_t)(wr * 128 + mi * 16 + lr) * NB;
#pragma unroll
        for (int ni = 0; ni < 4; ++ni) {
            const int col = bn + wc * 64 + ni * 16 + lq * 4;
            bf16x4 o = {(bf16_t)(acc[mi][ni][0] + bv[ni].x),
                        (bf16_t)(acc[mi][ni][1] + bv[ni].y),
                        (bf16_t)(acc[mi][ni][2] + bv[ni].z),
                        (bf16_t)(acc[mi][ni][3] + bv[ni].w)};
            *(bf16x4*)(Cp + rowoff + col) = o;
        }
    }
}

// ---------- scan pass A: per-segment local scan (h0 = 0) ----------
__global__ __launch_bounds__(256) void scan_seg_local(
    const float* __restrict__ u, const float* __restrict__ dt,
    const bf16_t* __restrict__ Bt_c, const float* __restrict__ log_A,
    float* __restrict__ pseg, float* __restrict__ hseg, int CL, int l0)
{
    const int tid = threadIdx.x;
    const int g = tid >> 4, n = tid & 15;
    const int gid = blockIdx.x * 16 + g;
    const int ch = gid & (NCH - 1);
    const int s = gid >> 11;
    const int b = ch >> 10, d = ch & (Dd - 1);

    const float A = -__expf(log_A[d * Nn + n]);
    const float rA = 1.f / A;

    size_t idx_bn = (size_t)(b * CL + s * SL) * NB + d * Nn + n;
    size_t idx_u = ((size_t)b * Ll + l0 + s * SL) * Dd + d;

    float p = 1.f, h = 0.f;
    for (int l = 0; l < SL; ++l) {
        const float dtv = dt[idx_u];
        const float uv = u[idx_u];
        const float bv = (float)Bt_c[idx_bn];
        const float a = __expf(dtv * A);
        p *= a;
        h = a * h + (a - 1.f) * rA * bv * uv;
        idx_bn += NB; idx_u += Dd;
    }
    const size_t o = ((size_t)s * NCH + ch) * Nn + n;
    pseg[o] = p;
    hseg[o] = h;
}

// ---------- scan pass B: sequential combine across segments ----------
__global__ __launch_bounds__(256) void scan_combine(
    const float* __restrict__ pseg, const float* __restrict__ hseg,
    float* __restrict__ hin_arr, float* __restrict__ h_state,
    int NSEG, int l0)
{
    const int t = blockIdx.x * 256 + threadIdx.x;
    float hin = (l0 == 0) ? 0.f : h_state[t];
    for (int s = 0; s < NSEG; ++s) {
        const size_t o = (size_t)s * (NCH * Nn) + t;
        hin_arr[o] = hin;
        hin = pseg[o] * hin + hseg[o];
    }
    h_state[t] = hin;
}

// ---------- scan pass C: re-run segment from correct h_in, emit y ----------
__global__ __launch_bounds__(256) void scan_seg_final(
    const float* __restrict__ u, const float* __restrict__ dt,
    const bf16_t* __restrict__ Bt_c, const bf16_t* __restrict__ Ct_c,
    const float* __restrict__ log_A, const float* __restrict__ D_skip,
    const float* __restrict__ hin_arr, float* __restrict__ y, int CL, int l0)
{
    const int tid = threadIdx.x;
    const int g = tid >> 4, n = tid & 15;
    const int gid = blockIdx.x * 16 + g;
    const int ch = gid & (NCH - 1);
    const int s = gid >> 11;
    const int b = ch >> 10, d = ch & (Dd - 1);

    const float A = -__expf(log_A[d * Nn + n]);
    const float rA = 1.f / A;
    const float Dsk = D_skip[d];

    size_t idx_bn = (size_t)(b * CL + s * SL) * NB + d * Nn + n;
    size_t idx_u = ((size_t)b * Ll + l0 + s * SL) * Dd + d;

    float h = hin_arr[((size_t)s * NCH + ch) * Nn + n];
    for (int l = 0; l < SL; ++l) {
        const float dtv = dt[idx_u];
        const float uv = u[idx_u];
        const float bv = (float)Bt_c[idx_bn];
        const float cv = (float)Ct_c[idx_bn];
        const float a = __expf(dtv * A);
        h = a * h + (a - 1.f) * rA * bv * uv;
        float p = cv * h;
        p += __shfl_xor(p, 1);
        p += __shfl_xor(p, 2);
        p += __shfl_xor(p, 4);
        p += __shfl_xor(p, 8);
        if (n == 0) y[idx_u] = p + Dsk * uv;
        idx_bn += NB; idx_u += Dd;
    }
}

// ---------- host ----------
static inline size_t al256(size_t x) { return (x + 255) & ~(size_t)255; }

extern "C" void kernel_launch(void* const* d_in, const int* in_sizes, int n_in,
                              void* d_out, int out_size, void* d_ws, size_t ws_size,
                              hipStream_t stream) {
    const float* u       = (const float*)d_in[0];
    const float* log_A   = (const float*)d_in[1];
    const float* D_skip  = (const float*)d_in[2];
    const float* dt_bias = (const float*)d_in[3];
    const float* W_dt    = (const float*)d_in[4];
    const float* b_dt    = (const float*)d_in[5];
    const float* W_B     = (const float*)d_in[6];
    const float* b_B     = (const float*)d_in[7];
    const float* W_C     = (const float*)d_in[8];
    const float* b_C     = (const float*)d_in[9];
    float* y = (float*)d_out;

    // allow 128 KiB dynamic LDS for gemm256_bc (capture-safe host call)
    hipFuncSetAttribute(reinterpret_cast<const void*>(gemm256_bc),
                        hipFuncAttributeMaxDynamicSharedMemorySize, 131072);

    const size_t sz_ubf  = al256((size_t)Bb * Ll * Dd * 2);
    const size_t sz_w    = al256((size_t)NB * Dd * 2);
    const size_t sz_h    = al256((size_t)NCH * Nn * 4);
    const size_t sz_dtf  = al256((size_t)Bb * Ll * Dd * 4);
    const size_t sz_ucat = al256((size_t)Bb * Ll * KCAT * 2);
    const size_t sz_wcat = al256((size_t)Dd * KCAT * 2);

    int CL = 128;
    const int cands[5] = {2048, 1024, 512, 256, 128};
    for (int i = 0; i < 5; ++i) {
        const int c = cands[i];
        const int nseg = c / SL;
        const size_t seg = 3 * al256((size_t)nseg * NCH * Nn * 4);
        const size_t chunk = 2 * al256((size_t)2 * c * NB * 2);
        const size_t ovl = sz_ucat + sz_wcat;
        const size_t need = sz_ubf + 2 * sz_w + sz_h + sz_dtf + seg +
                            (chunk > ovl ? chunk : ovl);
        if (need <= ws_size) { CL = c; break; }
    }
    const int NSEG = CL / SL;

    char* p = (char*)d_ws;
    bf16_t* u_bf   = (bf16_t*)p; p += sz_ubf;
    bf16_t* wB_bf  = (bf16_t*)p; p += sz_w;
    bf16_t* wC_bf  = (bf16_t*)p; p += sz_w;
    float* h_state = (float*)p; p += sz_h;
    float* dt_full = (float*)p; p += sz_dtf;
    const size_t sz_seg1 = al256((size_t)NSEG * NCH * Nn * 4);
    float* pseg    = (float*)p; p += sz_seg1;
    float* hseg    = (float*)p; p += sz_seg1;
    float* hin_arr = (float*)p; p += sz_seg1;
    char* chunk0 = p;
    bf16_t* Bt_c = (bf16_t*)chunk0;
    bf16_t* Ct_c = (bf16_t*)(chunk0 + al256((size_t)2 * CL * NB * 2));
    bf16_t* u_cat = (bf16_t*)chunk0;
    bf16_t* w_cat = (bf16_t*)(chunk0 + sz_ucat);

    cvt_bf16<<<2048, 256, 0, stream>>>(u, u_bf, Bb * Ll * Dd / 4);
    cvt_bf16<<<2048, 256, 0, stream>>>(W_B, wB_bf, NB * Dd / 4);
    cvt_bf16<<<2048, 256, 0, stream>>>(W_C, wC_bf, NB * Dd / 4);
    build_ucat<<<Bb * Ll * Dd / 4 / 256, 256, 0, stream>>>(u, u_cat);
    build_wcat<<<Dd * Dd / 4 / 256, 256, 0, stream>>>(W_dt, w_cat);

    // dt GEMM: 128x64 tiles -> 512 blocks = 2 blocks/CU
    gemm_dt<<<dim3(Dd / 64, Bb * Ll / 128), 256, 0, stream>>>(
        u_cat, KCAT, w_cat, b_dt, dt_bias, dt_full);

    const bool use256 = (CL % 256 == 0);
    for (int l0 = 0; l0 < Ll; l0 += CL) {
        if (use256) {
            const int NY = 2 * CL / 256;
            gemm256_bc<<<dim3(128 * NY), 512, 131072, stream>>>(
                u_bf, CL, l0, Dd, wB_bf, wC_bf, b_B, b_C, Bt_c, Ct_c);
        } else {
            gemm_mfma<0, bf16_t><<<dim3(NB / 128, 2 * CL / 128), 256, 0, stream>>>(
                u_bf, CL, l0, Dd, wB_bf, b_B, nullptr, Bt_c, NB);
            gemm_mfma<0, bf16_t><<<dim3(NB / 128, 2 * CL / 128), 256, 0, stream>>>(
                u_bf, CL, l0, Dd, wC_bf, b_C, nullptr, Ct_c, NB);
        }
        scan_seg_local<<<dim3(128 * NSEG), 256, 0, stream>>>(
            u, dt_full, Bt_c, log_A, pseg, hseg, CL, l0);
        scan_combine<<<dim3(128), 256, 0, stream>>>(
            pseg, hseg, hin_arr, h_state, NSEG, l0);
        scan_seg_final<<<dim3(128 * NSEG), 256, 0, stream>>>(
            u, dt_full, Bt_c, Ct_c, log_A, D_skip, hin_arr, y, CL, l0);
    }
}